// Round 1
// baseline (298.640 us; speedup 1.0000x reference)
//
#include <hip/hip_runtime.h>

// Problem constants (B,L,H,D fixed by setup_inputs; S=u=40 from FACTOR*ceil(ln L))
constexpr int B = 4;
constexpr int L = 2048;
constexpr int H = 8;
constexpr int D = 64;
constexpr int S = 40;   // sampled keys per query
constexpr int U = 40;   // top-k queries
constexpr int HD = H * D;          // 512
constexpr int NC = 16;             // cumsum chunks
constexpr int CL = L / NC;         // 128

// ---------------------------------------------------------------------------
// K1: M[b,h,q] = max_s(Q.K_sample) - sum_s(Q.K_sample)/L   ; also zero flags.
// One wave per query. Lane layout: lane = s_sub*16 + d_sub (4 keys x 16 dims).
// ---------------------------------------------------------------------------
__global__ __launch_bounds__(256) void k_scores(
    const float* __restrict__ Q, const float* __restrict__ K,
    const int* __restrict__ idxs, float* __restrict__ M, int* __restrict__ flags)
{
    int wave = blockIdx.x * 4 + (threadIdx.x >> 6);
    int lane = threadIdx.x & 63;
    int q  = wave & (L - 1);
    int bh = wave / L;              // 0..31
    int b = bh >> 3, h = bh & 7;
    int s_sub = lane >> 4;          // 0..3
    int d_sub = lane & 15;          // 0..15

    const float* qp = Q + ((size_t)(b * L + q) * H + h) * D;
    float q0 = qp[d_sub], q1 = qp[d_sub + 16], q2 = qp[d_sub + 32], q3 = qp[d_sub + 48];

    const int* ip = idxs + q * S;
    float mx = -INFINITY, sm = 0.f;
    for (int t = 0; t < S / 4; ++t) {
        int s  = t * 4 + s_sub;
        int ki = ip[s];
        const float* kp = K + ((size_t)(b * L + ki) * H + h) * D;
        float acc = q0 * kp[d_sub] + q1 * kp[d_sub + 16]
                  + q2 * kp[d_sub + 32] + q3 * kp[d_sub + 48];
        // reduce across the 16-lane d group
        acc += __shfl_xor(acc, 1);
        acc += __shfl_xor(acc, 2);
        acc += __shfl_xor(acc, 4);
        acc += __shfl_xor(acc, 8);
        mx = fmaxf(mx, acc);
        sm += acc;
    }
    // combine the 4 s-groups
    mx = fmaxf(mx, __shfl_xor(mx, 16));
    mx = fmaxf(mx, __shfl_xor(mx, 32));
    sm += __shfl_xor(sm, 16);
    sm += __shfl_xor(sm, 32);

    if (lane == 0) {
        M[bh * L + q] = mx - sm * (1.0f / (float)L);
        flags[bh * L + q] = 0;
    }
}

// ---------------------------------------------------------------------------
// K2: per (b,h): sequential top-40 argmax (value desc, index asc — matches
// jax.lax.top_k order), then fused triangle attention. Row r only attends to
// keys 0..r (causal mask over rank, per reference), so only keys/values 0..39
// are needed. Writes upd[bh][r][d] and flags[bh*L + qidx] = r+1.
// ---------------------------------------------------------------------------
__global__ __launch_bounds__(256) void k_topk_attn(
    const float* __restrict__ Q, const float* __restrict__ K,
    const float* __restrict__ V, const float* __restrict__ M,
    int* __restrict__ flags, float* __restrict__ upd)
{
    __shared__ float Ms[L];
    __shared__ float Ks[U * D];
    __shared__ float Vs[U * D];
    __shared__ int   top_idx[U];
    __shared__ float redv[4];
    __shared__ int   redi[4];

    int bh = blockIdx.x;
    int b = bh >> 3, h = bh & 7;
    int tid = threadIdx.x;
    int lane = tid & 63, w = tid >> 6;

    for (int i = tid; i < L; i += 256) Ms[i] = M[bh * L + i];
    for (int i = tid; i < U * D; i += 256) {
        int k = i >> 6, d = i & 63;
        size_t g = ((size_t)(b * L + k) * H + h) * D + d;
        Ks[i] = K[g];
        Vs[i] = V[g];
    }
    __syncthreads();

    // ---- top-40 by sequential argmax ----
    for (int r = 0; r < U; ++r) {
        float bv = -INFINITY; int bi = L;
        for (int j = tid; j < L; j += 256) {
            float v = Ms[j];
            if (v > bv || (v == bv && j < bi)) { bv = v; bi = j; }
        }
        for (int off = 1; off < 64; off <<= 1) {
            float ov = __shfl_xor(bv, off);
            int   oi = __shfl_xor(bi, off);
            if (ov > bv || (ov == bv && oi < bi)) { bv = ov; bi = oi; }
        }
        if (lane == 0) { redv[w] = bv; redi[w] = bi; }
        __syncthreads();
        if (tid == 0) {
            float v0 = redv[0]; int i0 = redi[0];
            for (int k = 1; k < 4; ++k)
                if (redv[k] > v0 || (redv[k] == v0 && redi[k] < i0)) { v0 = redv[k]; i0 = redi[k]; }
            top_idx[r] = i0;
            Ms[i0] = -INFINITY;
        }
        __syncthreads();
    }

    // ---- triangle attention: wave w handles rows w, w+4, ... ----
    const float scale = 0.125f;  // 1/sqrt(64)
    for (int r = w; r < U; r += 4) {
        int qidx = top_idx[r];
        float qv = Q[((size_t)(b * L + qidx) * H + h) * D + lane];
        float myscore = -INFINITY;
        for (int k = 0; k <= r; ++k) {
            float p = qv * Ks[k * 64 + lane];
            p += __shfl_xor(p, 1);
            p += __shfl_xor(p, 2);
            p += __shfl_xor(p, 4);
            p += __shfl_xor(p, 8);
            p += __shfl_xor(p, 16);
            p += __shfl_xor(p, 32);
            if (lane == k) myscore = p * scale;
        }
        float m = myscore;
        for (int off = 1; off < 64; off <<= 1) m = fmaxf(m, __shfl_xor(m, off));
        float wgt = (lane <= r) ? expf(myscore - m) : 0.f;
        float ssum = wgt;
        for (int off = 1; off < 64; off <<= 1) ssum += __shfl_xor(ssum, off);
        float p = wgt / ssum;
        float o = 0.f;
        for (int k = 0; k <= r; ++k) {
            float pk = __shfl(p, k, 64);
            o += pk * Vs[k * 64 + lane];
        }
        upd[((size_t)bh * U + r) * D + lane] = o;
        if (lane == 0) flags[bh * L + qidx] = r + 1;
    }
}

// ---------------------------------------------------------------------------
// K3: per-chunk sums of V along L (for the cumsum).
// ---------------------------------------------------------------------------
__global__ __launch_bounds__(512) void k_chunksum(
    const float* __restrict__ V, float* __restrict__ partial)
{
    int b = blockIdx.x >> 4;     // NC = 16
    int c = blockIdx.x & 15;
    int hd = threadIdx.x;
    const float* vp = V + ((size_t)(b * L + c * CL)) * HD + hd;
    float s = 0.f;
    for (int l = 0; l < CL; ++l) s += vp[(size_t)l * HD];
    partial[((size_t)b * NC + c) * HD + hd] = s;
}

// ---------------------------------------------------------------------------
// K4: final write: out[b,l,h,d] = cumsum(V)[b,:,h,d] up to l, except rows
// flagged as top-k, which get the attention update (scatter fused here).
// ---------------------------------------------------------------------------
__global__ __launch_bounds__(512) void k_cumsum_out(
    const float* __restrict__ V, const float* __restrict__ partial,
    const int* __restrict__ flags, const float* __restrict__ upd,
    float* __restrict__ out)
{
    int b = blockIdx.x >> 4;
    int c = blockIdx.x & 15;
    int hd = threadIdx.x;
    int h = hd >> 6, d = hd & 63;

    float acc = 0.f;
    for (int cc = 0; cc < c; ++cc)
        acc += partial[((size_t)b * NC + cc) * HD + hd];

    const float* vp = V + ((size_t)(b * L + c * CL)) * HD + hd;
    float*       op = out + ((size_t)(b * L + c * CL)) * HD + hd;
    const int*   fp = flags + (b * H + h) * L + c * CL;
    const float* up = upd + (size_t)(b * H + h) * U * D + d;

    for (int l = 0; l < CL; ++l) {
        acc += vp[(size_t)l * HD];
        int f = fp[l];
        op[(size_t)l * HD] = f ? up[(size_t)(f - 1) * D] : acc;
    }
}

extern "C" void kernel_launch(void* const* d_in, const int* in_sizes, int n_in,
                              void* d_out, int out_size, void* d_ws, size_t ws_size,
                              hipStream_t stream)
{
    const float* Q   = (const float*)d_in[0];
    const float* K   = (const float*)d_in[1];
    const float* V   = (const float*)d_in[2];
    const int*  idxs = (const int*)d_in[3];
    float* out = (float*)d_out;

    char* ws = (char*)d_ws;
    float* M       = (float*)(ws);                       // B*H*L floats   = 256 KB
    int*   flags   = (int*)  (ws + 256 * 1024);          // B*H*L ints     = 256 KB
    float* upd     = (float*)(ws + 512 * 1024);          // B*H*U*D floats = 320 KB
    float* partial = (float*)(ws + 832 * 1024);          // B*NC*HD floats = 128 KB

    k_scores    <<<B * H * L / 4, 256, 0, stream>>>(Q, K, idxs, M, flags);
    k_topk_attn <<<B * H,         256, 0, stream>>>(Q, K, V, M, flags, upd);
    k_chunksum  <<<B * NC,        512, 0, stream>>>(V, partial);
    k_cumsum_out<<<B * NC,        512, 0, stream>>>(V, partial, flags, upd, out);
}

// Round 2
// 189.949 us; speedup vs baseline: 1.5722x; 1.5722x over previous
//
#include <hip/hip_runtime.h>
#include <stdint.h>

constexpr int B = 4;
constexpr int L = 2048;
constexpr int H = 8;
constexpr int D = 64;
constexpr int S = 40;    // sampled keys per query
constexpr int U = 40;    // top-k queries
constexpr int HD = H * D;          // 512
constexpr int NSEG = 8;            // top-k segments per (b,h)
constexpr int SEGL = L / NSEG;     // 256
constexpr int NC = 64;             // cumsum chunks
constexpr int CL = L / NC;         // 32

// monotone float->uint mapping: larger float => larger uint
__device__ __forceinline__ unsigned mono(float v) {
    unsigned u = __float_as_uint(v);
    return (u & 0x80000000u) ? ~u : (u | 0x80000000u);
}

// ---------------------------------------------------------------------------
// K1: M[b,h,q] = max_s(Q.K_sample) - sum_s(Q.K_sample)/L ; zero flags.
// One wave per query; lane = s_sub*16 + d4 (4 keys x 16 float4-dims).
// ---------------------------------------------------------------------------
__global__ __launch_bounds__(256) void k_scores(
    const float4* __restrict__ Q4, const float4* __restrict__ K4,
    const int* __restrict__ idxs, float* __restrict__ M, int* __restrict__ flags)
{
    int wave = blockIdx.x * 4 + (threadIdx.x >> 6);
    int lane = threadIdx.x & 63;
    int q  = wave & (L - 1);
    int bh = wave >> 11;            // 0..31
    int b = bh >> 3, h = bh & 7;
    int s_sub = lane >> 4;          // 0..3
    int d4 = lane & 15;             // float4 index 0..15

    float4 qv = Q4[((size_t)(b * L + q) * H + h) * 16 + d4];
    const int* ip = idxs + q * S;
    float mx = -INFINITY, sm = 0.f;
    #pragma unroll
    for (int t = 0; t < S / 4; ++t) {
        int ki = ip[t * 4 + s_sub];
        float4 kv = K4[((size_t)(b * L + ki) * H + h) * 16 + d4];
        float acc = qv.x * kv.x + qv.y * kv.y + qv.z * kv.z + qv.w * kv.w;
        acc += __shfl_xor(acc, 1);
        acc += __shfl_xor(acc, 2);
        acc += __shfl_xor(acc, 4);
        acc += __shfl_xor(acc, 8);
        mx = fmaxf(mx, acc);
        sm += acc;
    }
    mx = fmaxf(mx, __shfl_xor(mx, 16));
    mx = fmaxf(mx, __shfl_xor(mx, 32));
    sm += __shfl_xor(sm, 16);
    sm += __shfl_xor(sm, 32);

    if (lane == 0) {
        M[bh * L + q] = mx - sm * (1.0f / (float)L);
        flags[bh * L + q] = 0;
    }
}

// ---------------------------------------------------------------------------
// K2: per-segment exact top-40 by rank counting (no dependent chains).
// 1 wave per block, 4 elements per lane. rank(x) = #{y : y > x} with
// (value desc, index asc) order; ranks are unique => ranks 0..39 fill the
// sorted candidate list cand[blk][0..39] as packed (mono<<32)|~index.
// ---------------------------------------------------------------------------
__global__ __launch_bounds__(64) void k_seg_topk(
    const float* __restrict__ M, unsigned long long* __restrict__ cand)
{
    int blk = blockIdx.x;           // bh*NSEG + seg
    int bh = blk >> 3, seg = blk & 7;
    int lane = threadIdx.x;
    int j0 = seg * SEGL + lane * 4;

    float4 v = *(const float4*)(M + (size_t)bh * L + j0);
    unsigned m[4] = { mono(v.x), mono(v.y), mono(v.z), mono(v.w) };
    int rank[4] = { 0, 0, 0, 0 };

    #pragma unroll 4
    for (int src = 0; src < 64; ++src) {
        #pragma unroll
        for (int slot = 0; slot < 4; ++slot) {
            unsigned bm = __shfl(m[slot], src);
            int bj = src * 4 + slot;
            #pragma unroll
            for (int s = 0; s < 4; ++s) {
                int myj = lane * 4 + s;
                rank[s] += (bm > m[s]) || (bm == m[s] && bj < myj);
            }
        }
    }

    unsigned long long* out = cand + (size_t)blk * U;
    #pragma unroll
    for (int s = 0; s < 4; ++s)
        if (rank[s] < U)
            out[rank[s]] = ((unsigned long long)m[s] << 32)
                         | (unsigned)(~(unsigned)(j0 + s));
}

// ---------------------------------------------------------------------------
// K3: per (b,h): top-40 of 320 candidates by rank counting, then fully
// parallel 40x40 triangle attention in LDS. Writes upd and flags (rank+1).
// ---------------------------------------------------------------------------
__global__ __launch_bounds__(256) void k_attn(
    const float4* __restrict__ Q4, const float4* __restrict__ K4,
    const float4* __restrict__ V4, const unsigned long long* __restrict__ cand,
    int* __restrict__ flags, float* __restrict__ upd)
{
    __shared__ unsigned long long cnd[NSEG * U];   // 320
    __shared__ int top_idx[U];
    __shared__ __align__(16) float Qs[U * 68];
    __shared__ __align__(16) float Ks[U * 68];
    __shared__ __align__(16) float Vs[U * 68];
    __shared__ float P[U * 41];

    int bh = blockIdx.x;
    int b = bh >> 3, h = bh & 7;
    int tid = threadIdx.x;

    for (int i = tid; i < NSEG * U; i += 256)
        cnd[i] = cand[(size_t)bh * NSEG * U + i];
    __syncthreads();

    // rank-select top-40 of 320 (keys unique => ranks unique)
    {
        unsigned long long ka = cnd[tid < NSEG * U ? tid : 0];
        unsigned long long kb = (tid < NSEG * U - 256) ? cnd[256 + tid] : 0ULL;
        int ra = 0, rb = 0;
        for (int j = 0; j < NSEG * U; ++j) {
            unsigned long long kj = cnd[j];
            ra += (kj > ka);
            rb += (kj > kb);
        }
        if (tid < NSEG * U && ra < U) top_idx[ra] = (int)(~(unsigned)ka);
        if (tid < NSEG * U - 256 && rb < U) top_idx[rb] = (int)(~(unsigned)kb);
    }
    __syncthreads();

    if (tid < U) flags[bh * L + top_idx[tid]] = tid + 1;

    // stage K[0..39], V[0..39], Q[top_idx[r]] rows into LDS (stride 68 floats)
    for (int i = tid; i < U * 16; i += 256) {
        int r = i >> 4, d4 = i & 15;
        size_t kvbase = ((size_t)(b * L + r) * H + h) * 16 + d4;
        *(float4*)(Ks + r * 68 + d4 * 4) = K4[kvbase];
        *(float4*)(Vs + r * 68 + d4 * 4) = V4[kvbase];
        *(float4*)(Qs + r * 68 + d4 * 4) =
            Q4[((size_t)(b * L + top_idx[r]) * H + h) * 16 + d4];
    }
    __syncthreads();

    // scores: S[r][k] for k <= r (causal over rank, per reference)
    const float scale = 0.125f;   // 1/sqrt(64)
    for (int p = tid; p < U * U; p += 256) {
        int r = p / U, k = p - r * U;
        if (k <= r) {
            float acc = 0.f;
            #pragma unroll
            for (int d = 0; d < D; d += 4) {
                float4 a = *(const float4*)(Qs + r * 68 + d);
                float4 c = *(const float4*)(Ks + k * 68 + d);
                acc += a.x * c.x + a.y * c.y + a.z * c.z + a.w * c.w;
            }
            P[r * 41 + k] = acc * scale;
        }
    }
    __syncthreads();

    // row softmax over k <= r
    if (tid < U) {
        int r = tid;
        float mval = -INFINITY;
        for (int k = 0; k <= r; ++k) mval = fmaxf(mval, P[r * 41 + k]);
        float ssum = 0.f;
        for (int k = 0; k <= r; ++k) {
            float e = expf(P[r * 41 + k] - mval);
            P[r * 41 + k] = e;
            ssum += e;
        }
        float inv = 1.f / ssum;
        for (int k = 0; k <= r; ++k) P[r * 41 + k] *= inv;
    }
    __syncthreads();

    // upd[r][d] = sum_{k<=r} P[r][k] * V[k][d]; wave w handles r = w, w+4, ...
    for (int t = tid; t < U * D; t += 256) {
        int r = t >> 6, d = t & 63;
        for (; r < U; r += 4) {
            float acc = 0.f;
            for (int k = 0; k <= r; ++k) acc += P[r * 41 + k] * Vs[k * 68 + d];
            upd[((size_t)bh * U + r) * D + d] = acc;
        }
        break;
    }
}

// ---------------------------------------------------------------------------
// K4: per-chunk sums of V along L.
// ---------------------------------------------------------------------------
__global__ __launch_bounds__(512) void k_chunksum(
    const float* __restrict__ V, float* __restrict__ partial)
{
    int b = blockIdx.x >> 6;        // NC = 64
    int c = blockIdx.x & 63;
    int hd = threadIdx.x;
    const float* vp = V + ((size_t)(b * L + c * CL)) * HD + hd;
    float s = 0.f;
    #pragma unroll
    for (int l = 0; l < CL; ++l) s += vp[(size_t)l * HD];
    partial[((size_t)b * NC + c) * HD + hd] = s;
}

// ---------------------------------------------------------------------------
// K5: out[b,l,h,d] = cumsum(V) with flagged rows replaced by attention upd.
// ---------------------------------------------------------------------------
__global__ __launch_bounds__(512) void k_cumsum_out(
    const float* __restrict__ V, const float* __restrict__ partial,
    const int* __restrict__ flags, const float* __restrict__ upd,
    float* __restrict__ out)
{
    int b = blockIdx.x >> 6;
    int c = blockIdx.x & 63;
    int hd = threadIdx.x;
    int h = hd >> 6, d = hd & 63;

    float acc = 0.f;
    for (int cc = 0; cc < c; ++cc)
        acc += partial[((size_t)b * NC + cc) * HD + hd];

    const float* vp = V + ((size_t)(b * L + c * CL)) * HD + hd;
    float*       op = out + ((size_t)(b * L + c * CL)) * HD + hd;
    const int*   fp = flags + (b * H + h) * L + c * CL;
    const float* up = upd + (size_t)(b * H + h) * U * D + d;

    #pragma unroll 4
    for (int l = 0; l < CL; ++l) {
        acc += vp[(size_t)l * HD];
        int f = fp[l];
        op[(size_t)l * HD] = f ? up[(size_t)(f - 1) * D] : acc;
    }
}

extern "C" void kernel_launch(void* const* d_in, const int* in_sizes, int n_in,
                              void* d_out, int out_size, void* d_ws, size_t ws_size,
                              hipStream_t stream)
{
    const float* Q   = (const float*)d_in[0];
    const float* K   = (const float*)d_in[1];
    const float* V   = (const float*)d_in[2];
    const int*  idxs = (const int*)d_in[3];
    float* out = (float*)d_out;

    char* ws = (char*)d_ws;
    float* M       = (float*)(ws);                         // B*H*L          = 256 KB
    int*   flags   = (int*)  (ws + 262144);                // B*H*L          = 256 KB
    float* upd     = (float*)(ws + 524288);                // B*H*U*D        = 320 KB
    float* partial = (float*)(ws + 851968);                // B*NC*HD        = 512 KB
    unsigned long long* cand = (unsigned long long*)(ws + 1376256); // 80 KB

    k_scores    <<<B * H * L / 4, 256, 0, stream>>>((const float4*)Q, (const float4*)K, idxs, M, flags);
    k_seg_topk  <<<B * H * NSEG,   64, 0, stream>>>(M, cand);
    k_attn      <<<B * H,         256, 0, stream>>>((const float4*)Q, (const float4*)K, (const float4*)V,
                                                    cand, flags, upd);
    k_chunksum  <<<B * NC,        512, 0, stream>>>(V, partial);
    k_cumsum_out<<<B * NC,        512, 0, stream>>>(V, partial, flags, upd, out);
}

// Round 3
// 174.312 us; speedup vs baseline: 1.7133x; 1.0897x over previous
//
#include <hip/hip_runtime.h>
#include <stdint.h>

constexpr int B = 4;
constexpr int L = 2048;
constexpr int H = 8;
constexpr int D = 64;
constexpr int S = 40;    // sampled keys per query
constexpr int U = 40;    // top-k queries
constexpr int HD = H * D;          // 512
constexpr int NSEG = 8;            // top-k segments per (b,h)
constexpr int SEGL = L / NSEG;     // 256
constexpr int NC = 64;             // cumsum chunks
constexpr int CL = L / NC;         // 32

// monotone float->uint mapping: larger float => larger uint
__device__ __forceinline__ unsigned mono(float v) {
    unsigned u = __float_as_uint(v);
    return (u & 0x80000000u) ? ~u : (u | 0x80000000u);
}

// ---------------------------------------------------------------------------
// K1: M[b,h,q] = max_s(Q.K_sample) - sum_s(Q.K_sample)/L for ALL 8 heads at
// once. One wave per (b,q): lane = h*8+dd covers dims [8*lane..8*lane+7] of
// the contiguous 2 KB row K[b,ki,:,:] (two float4 loads per lane -> two
// contiguous 1 KB wave transactions per key, shared by all heads).
// XCD swizzle: b = (blockIdx%8)>>1 pins each b's 4 MB K slab to 2 XCDs.
// ---------------------------------------------------------------------------
__global__ __launch_bounds__(256) void k_scores(
    const float4* __restrict__ Q4, const float4* __restrict__ K4,
    const int* __restrict__ idxs, float* __restrict__ M)
{
    int i = blockIdx.x;                 // 0..2047
    int xcd = i & 7;
    int b = xcd >> 1;
    int qc = (i >> 3) * 2 + (xcd & 1);  // 0..511
    int w = threadIdx.x >> 6;
    int lane = threadIdx.x & 63;
    int q = qc * 4 + w;
    int h = lane >> 3;
    int dd = lane & 7;

    const float4* qrow = Q4 + (size_t)(b * L + q) * 128;
    float4 qa = qrow[2 * lane], qb = qrow[2 * lane + 1];

    int v_idx = idxs[q * S + (lane < S ? lane : 0)];

    const float4* kbase = K4 + (size_t)b * L * 128;
    float mx = -INFINITY, sm = 0.f;
    #pragma unroll 8
    for (int s = 0; s < S; ++s) {
        int ki = __shfl(v_idx, s);
        const float4* krow = kbase + (size_t)ki * 128;
        float4 ka = krow[2 * lane], kb = krow[2 * lane + 1];
        float d = qa.x * ka.x + qa.y * ka.y + qa.z * ka.z + qa.w * ka.w
                + qb.x * kb.x + qb.y * kb.y + qb.z * kb.z + qb.w * kb.w;
        d += __shfl_xor(d, 1);
        d += __shfl_xor(d, 2);
        d += __shfl_xor(d, 4);
        mx = fmaxf(mx, d);
        sm += d;
    }
    if (dd == 0)
        M[(b * 8 + h) * L + q] = mx - sm * (1.0f / (float)L);
}

// ---------------------------------------------------------------------------
// K2: per-segment exact top-40 by rank counting; also zeroes flags (int4).
// ---------------------------------------------------------------------------
__global__ __launch_bounds__(64) void k_seg_topk(
    const float* __restrict__ M, unsigned long long* __restrict__ cand,
    int* __restrict__ flags)
{
    int blk = blockIdx.x;           // bh*NSEG + seg
    int bh = blk >> 3, seg = blk & 7;
    int lane = threadIdx.x;
    int j0 = seg * SEGL + lane * 4;

    // zero flags for this segment (coalesced int4)
    *(int4*)(flags + (size_t)bh * L + j0) = make_int4(0, 0, 0, 0);

    float4 v = *(const float4*)(M + (size_t)bh * L + j0);
    unsigned m[4] = { mono(v.x), mono(v.y), mono(v.z), mono(v.w) };
    int rank[4] = { 0, 0, 0, 0 };

    #pragma unroll 4
    for (int src = 0; src < 64; ++src) {
        #pragma unroll
        for (int slot = 0; slot < 4; ++slot) {
            unsigned bm = __shfl(m[slot], src);
            int bj = src * 4 + slot;
            #pragma unroll
            for (int s = 0; s < 4; ++s) {
                int myj = lane * 4 + s;
                rank[s] += (bm > m[s]) || (bm == m[s] && bj < myj);
            }
        }
    }

    unsigned long long* out = cand + (size_t)blk * U;
    #pragma unroll
    for (int s = 0; s < 4; ++s)
        if (rank[s] < U)
            out[rank[s]] = ((unsigned long long)m[s] << 32)
                         | (unsigned)(~(unsigned)(j0 + s));
}

// ---------------------------------------------------------------------------
// K3: per (b,h): top-40 of 320 candidates by rank counting, then fully
// parallel 40x40 triangle attention in LDS. Writes upd and flags (rank+1).
// ---------------------------------------------------------------------------
__global__ __launch_bounds__(256) void k_attn(
    const float4* __restrict__ Q4, const float4* __restrict__ K4,
    const float4* __restrict__ V4, const unsigned long long* __restrict__ cand,
    int* __restrict__ flags, float* __restrict__ upd)
{
    __shared__ unsigned long long cnd[NSEG * U];   // 320
    __shared__ int top_idx[U];
    __shared__ __align__(16) float Qs[U * 68];
    __shared__ __align__(16) float Ks[U * 68];
    __shared__ __align__(16) float Vs[U * 68];
    __shared__ float P[U * 41];

    int bh = blockIdx.x;
    int b = bh >> 3, h = bh & 7;
    int tid = threadIdx.x;

    for (int i = tid; i < NSEG * U; i += 256)
        cnd[i] = cand[(size_t)bh * NSEG * U + i];
    __syncthreads();

    // rank-select top-40 of 320 (keys unique => ranks unique)
    {
        unsigned long long ka = cnd[tid < NSEG * U ? tid : 0];
        unsigned long long kb = (tid < NSEG * U - 256) ? cnd[256 + tid] : 0ULL;
        int ra = 0, rb = 0;
        for (int j = 0; j < NSEG * U; ++j) {
            unsigned long long kj = cnd[j];
            ra += (kj > ka);
            rb += (kj > kb);
        }
        if (tid < NSEG * U && ra < U) top_idx[ra] = (int)(~(unsigned)ka);
        if (tid < NSEG * U - 256 && rb < U) top_idx[rb] = (int)(~(unsigned)kb);
    }
    __syncthreads();

    if (tid < U) flags[bh * L + top_idx[tid]] = tid + 1;

    // stage K[0..39], V[0..39], Q[top_idx[r]] rows into LDS (stride 68 floats)
    for (int i = tid; i < U * 16; i += 256) {
        int r = i >> 4, d4 = i & 15;
        size_t kvbase = ((size_t)(b * L + r) * H + h) * 16 + d4;
        *(float4*)(Ks + r * 68 + d4 * 4) = K4[kvbase];
        *(float4*)(Vs + r * 68 + d4 * 4) = V4[kvbase];
        *(float4*)(Qs + r * 68 + d4 * 4) =
            Q4[((size_t)(b * L + top_idx[r]) * H + h) * 16 + d4];
    }
    __syncthreads();

    // scores: S[r][k] for k <= r (causal over rank, per reference)
    const float scale = 0.125f;   // 1/sqrt(64)
    for (int p = tid; p < U * U; p += 256) {
        int r = p / U, k = p - r * U;
        if (k <= r) {
            float acc = 0.f;
            #pragma unroll
            for (int d = 0; d < D; d += 4) {
                float4 a = *(const float4*)(Qs + r * 68 + d);
                float4 c = *(const float4*)(Ks + k * 68 + d);
                acc += a.x * c.x + a.y * c.y + a.z * c.z + a.w * c.w;
            }
            P[r * 41 + k] = acc * scale;
        }
    }
    __syncthreads();

    // row softmax over k <= r
    if (tid < U) {
        int r = tid;
        float mval = -INFINITY;
        for (int k = 0; k <= r; ++k) mval = fmaxf(mval, P[r * 41 + k]);
        float ssum = 0.f;
        for (int k = 0; k <= r; ++k) {
            float e = expf(P[r * 41 + k] - mval);
            P[r * 41 + k] = e;
            ssum += e;
        }
        float inv = 1.f / ssum;
        for (int k = 0; k <= r; ++k) P[r * 41 + k] *= inv;
    }
    __syncthreads();

    // upd[r][d] = sum_{k<=r} P[r][k] * V[k][d]
    for (int t = tid; t < U * D; t += 256) {
        int r = t >> 6, d = t & 63;
        float acc = 0.f;
        for (int k = 0; k <= r; ++k) acc += P[r * 41 + k] * Vs[k * 68 + d];
        upd[((size_t)bh * U + r) * D + d] = acc;
    }
}

// ---------------------------------------------------------------------------
// K4: per-chunk sums of V along L.
// ---------------------------------------------------------------------------
__global__ __launch_bounds__(512) void k_chunksum(
    const float* __restrict__ V, float* __restrict__ partial)
{
    int b = blockIdx.x >> 6;        // NC = 64
    int c = blockIdx.x & 63;
    int hd = threadIdx.x;
    const float* vp = V + ((size_t)(b * L + c * CL)) * HD + hd;
    float s = 0.f;
    #pragma unroll
    for (int l = 0; l < CL; ++l) s += vp[(size_t)l * HD];
    partial[((size_t)b * NC + c) * HD + hd] = s;
}

// ---------------------------------------------------------------------------
// K5: in-place exclusive scan of partial along the chunk axis.
// ---------------------------------------------------------------------------
__global__ __launch_bounds__(512) void k_scan(float* __restrict__ partial)
{
    int b = blockIdx.x;
    int hd = threadIdx.x;
    float acc = 0.f;
    #pragma unroll 8
    for (int c = 0; c < NC; ++c) {
        size_t o = ((size_t)b * NC + c) * HD + hd;
        float v = partial[o];
        partial[o] = acc;
        acc += v;
    }
}

// ---------------------------------------------------------------------------
// K6: out = cumsum(V) (base from scanned partial) with flagged rows replaced.
// ---------------------------------------------------------------------------
__global__ __launch_bounds__(512) void k_cumsum_out(
    const float* __restrict__ V, const float* __restrict__ partial,
    const int* __restrict__ flags, const float* __restrict__ upd,
    float* __restrict__ out)
{
    int b = blockIdx.x >> 6;
    int c = blockIdx.x & 63;
    int hd = threadIdx.x;
    int h = hd >> 6, d = hd & 63;

    float acc = partial[((size_t)b * NC + c) * HD + hd];

    const float* vp = V + ((size_t)(b * L + c * CL)) * HD + hd;
    float*       op = out + ((size_t)(b * L + c * CL)) * HD + hd;
    const int*   fp = flags + (b * H + h) * L + c * CL;
    const float* up = upd + (size_t)(b * H + h) * U * D + d;

    #pragma unroll 4
    for (int l = 0; l < CL; ++l) {
        acc += vp[(size_t)l * HD];
        int f = fp[l];
        op[(size_t)l * HD] = f ? up[(size_t)(f - 1) * D] : acc;
    }
}

extern "C" void kernel_launch(void* const* d_in, const int* in_sizes, int n_in,
                              void* d_out, int out_size, void* d_ws, size_t ws_size,
                              hipStream_t stream)
{
    const float* Q   = (const float*)d_in[0];
    const float* K   = (const float*)d_in[1];
    const float* V   = (const float*)d_in[2];
    const int*  idxs = (const int*)d_in[3];
    float* out = (float*)d_out;

    char* ws = (char*)d_ws;
    float* M       = (float*)(ws);                         // B*H*L          = 256 KB
    int*   flags   = (int*)  (ws + 262144);                // B*H*L          = 256 KB
    float* upd     = (float*)(ws + 524288);                // B*H*U*D        = 320 KB
    float* partial = (float*)(ws + 851968);                // B*NC*HD        = 512 KB
    unsigned long long* cand = (unsigned long long*)(ws + 1376256); // 80 KB

    k_scores    <<<B * L / 4,    256, 0, stream>>>((const float4*)Q, (const float4*)K, idxs, M);
    k_seg_topk  <<<B * H * NSEG,  64, 0, stream>>>(M, cand, flags);
    k_attn      <<<B * H,        256, 0, stream>>>((const float4*)Q, (const float4*)K, (const float4*)V,
                                                   cand, flags, upd);
    k_chunksum  <<<B * NC,       512, 0, stream>>>(V, partial);
    k_scan      <<<B,            512, 0, stream>>>(partial);
    k_cumsum_out<<<B * NC,       512, 0, stream>>>(V, partial, flags, upd, out);
}